// Round 4
// baseline (151.930 us; speedup 1.0000x reference)
//
#include <hip/hip_runtime.h>
#include <hip/hip_bf16.h>

// DeformableAttention: BS=4, Hq=Wq=64, C=256, M=8, K=4, L=4, CV=32
// SCALES = 64,32,16,8
//
// Dispatches (5):
//  D1 gemm_z_wp : z = bf16(q@Wz+bz)  AND  wp_l = feat_l@Wp+bp (bf16x3 split)
//  D2 gemm_zo_za: zo = bf16(z@Wo+bo) AND  za = bf16(z@Wa+ba)
//  D3 softmax   : za -> attn [b][p][m][16] f32
//  D4 sample    : level-uniform waves, XCD-swizzled blocks -> out_pre f32
//  D5 gemm final: out = out_pre@Wm+bm (bf16x3 split)
//
// ws layout (MB): z@0(8) za@8(4) zo@16(8) attn@28(8)
//   wp0@36(16) wp1@52(4) wp2@56(1) wp3@57(0.25); out_pre@0(16). Peak 57.25 MB.

typedef __attribute__((ext_vector_type(8))) short short8;
typedef __attribute__((ext_vector_type(4))) float f32x4;

constexpr int LDT = 40;  // LDS row stride (bf16 elems)

__device__ __forceinline__ short f2bf(float x) {
    unsigned u = __builtin_bit_cast(unsigned, x);
    unsigned r = (u + 0x7fffu + ((u >> 16) & 1u)) >> 16;
    return (short)r;
}
__device__ __forceinline__ float bf2f(short s) {
    unsigned u = ((unsigned)(unsigned short)s) << 16;
    return __builtin_bit_cast(float, u);
}

// ---------------------------------------------------------------------------
// GEMM body: C[tile 128x128 at (m0,n0)] = A[rows x 256] @ B[256 x N] + bias
// ---------------------------------------------------------------------------
template<typename AT, typename OT, bool SPLIT>
__device__ __forceinline__ void gemm_body(
    short* __restrict__ As, short* __restrict__ Bs,
    const AT* __restrict__ A, const float* __restrict__ B,
    const float* __restrict__ bias, OT* __restrict__ C,
    int N, int m0, int n0)
{
    short* Asl = As + 128 * LDT;
    short* Bsl = Bs + 128 * LDT;

    const int t    = threadIdx.x;
    const int lane = t & 63, wid = t >> 6;
    const int wr = wid >> 1, wc = wid & 1;
    const int lr = lane & 15, lkb = (lane >> 4) * 8;

    const int arow = t >> 1, akoff = (t & 1) * 16;
    const int bn = t & 127, bkoff = (t >> 7) * 16;

    f32x4 acc[4][4] = {};

    for (int kt = 0; kt < 256; kt += 32) {
        if constexpr (sizeof(AT) == 4) {
            const float* ap = (const float*)A + (size_t)(m0 + arow) * 256 + kt + akoff;
            float v[16];
            #pragma unroll
            for (int i = 0; i < 4; ++i) {
                float4 f = ((const float4*)ap)[i];
                v[4*i] = f.x; v[4*i+1] = f.y; v[4*i+2] = f.z; v[4*i+3] = f.w;
            }
            short8 h0, h1;
            #pragma unroll
            for (int i = 0; i < 8; ++i) { h0[i] = f2bf(v[i]); h1[i] = f2bf(v[8+i]); }
            *(short8*)&As[arow*LDT + akoff]     = h0;
            *(short8*)&As[arow*LDT + akoff + 8] = h1;
            if constexpr (SPLIT) {
                short8 l0, l1;
                #pragma unroll
                for (int i = 0; i < 8; ++i) {
                    l0[i] = f2bf(v[i]   - bf2f(h0[i]));
                    l1[i] = f2bf(v[8+i] - bf2f(h1[i]));
                }
                *(short8*)&Asl[arow*LDT + akoff]     = l0;
                *(short8*)&Asl[arow*LDT + akoff + 8] = l1;
            }
        } else {
            const short* ap = (const short*)A + (size_t)(m0 + arow) * 256 + kt + akoff;
            *(short8*)&As[arow*LDT + akoff]     = ((const short8*)ap)[0];
            *(short8*)&As[arow*LDT + akoff + 8] = ((const short8*)ap)[1];
        }
        {
            const float* bp = B + (size_t)(kt + bkoff) * N + n0 + bn;
            float v[16];
            #pragma unroll
            for (int i = 0; i < 16; ++i) v[i] = bp[(size_t)i * N];
            short8 h0, h1;
            #pragma unroll
            for (int i = 0; i < 8; ++i) { h0[i] = f2bf(v[i]); h1[i] = f2bf(v[8+i]); }
            *(short8*)&Bs[bn*LDT + bkoff]     = h0;
            *(short8*)&Bs[bn*LDT + bkoff + 8] = h1;
            if constexpr (SPLIT) {
                short8 l0, l1;
                #pragma unroll
                for (int i = 0; i < 8; ++i) {
                    l0[i] = f2bf(v[i]   - bf2f(h0[i]));
                    l1[i] = f2bf(v[8+i] - bf2f(h1[i]));
                }
                *(short8*)&Bsl[bn*LDT + bkoff]     = l0;
                *(short8*)&Bsl[bn*LDT + bkoff + 8] = l1;
            }
        }
        __syncthreads();

        short8 af[4], bfh[4];
        #pragma unroll
        for (int m = 0; m < 4; ++m)
            af[m] = *(const short8*)&As[(wr*64 + m*16 + lr)*LDT + lkb];
        #pragma unroll
        for (int n = 0; n < 4; ++n)
            bfh[n] = *(const short8*)&Bs[(wc*64 + n*16 + lr)*LDT + lkb];
        if constexpr (!SPLIT) {
            #pragma unroll
            for (int m = 0; m < 4; ++m)
                #pragma unroll
                for (int n = 0; n < 4; ++n)
                    acc[m][n] = __builtin_amdgcn_mfma_f32_16x16x32_bf16(af[m], bfh[n], acc[m][n], 0, 0, 0);
        } else {
            short8 afl[4], bfl[4];
            #pragma unroll
            for (int m = 0; m < 4; ++m)
                afl[m] = *(const short8*)&Asl[(wr*64 + m*16 + lr)*LDT + lkb];
            #pragma unroll
            for (int n = 0; n < 4; ++n)
                bfl[n] = *(const short8*)&Bsl[(wc*64 + n*16 + lr)*LDT + lkb];
            #pragma unroll
            for (int m = 0; m < 4; ++m)
                #pragma unroll
                for (int n = 0; n < 4; ++n) {
                    acc[m][n] = __builtin_amdgcn_mfma_f32_16x16x32_bf16(af[m],  bfh[n], acc[m][n], 0, 0, 0);
                    acc[m][n] = __builtin_amdgcn_mfma_f32_16x16x32_bf16(af[m],  bfl[n], acc[m][n], 0, 0, 0);
                    acc[m][n] = __builtin_amdgcn_mfma_f32_16x16x32_bf16(afl[m], bfh[n], acc[m][n], 0, 0, 0);
                }
        }
        __syncthreads();
    }

    #pragma unroll
    for (int n = 0; n < 4; ++n) {
        const int col = n0 + wc*64 + n*16 + lr;
        const float bv = bias[col];
        #pragma unroll
        for (int m = 0; m < 4; ++m) {
            #pragma unroll
            for (int r = 0; r < 4; ++r) {
                const int row = m0 + wr*64 + m*16 + (lane >> 4)*4 + r;
                const float v = acc[m][n][r] + bv;
                if constexpr (sizeof(OT) == 4)
                    ((float*)C)[(size_t)row * N + col] = v;
                else
                    ((short*)C)[(size_t)row * N + col] = f2bf(v);
            }
        }
    }
}

// D1: z GEMM (by<128) + all 4 wp GEMMs (by>=128), one dispatch
__global__ __launch_bounds__(256) void gemm_z_wp(
    const float* __restrict__ q, const float* __restrict__ Wz,
    const float* __restrict__ bz, short* __restrict__ z,
    const float* __restrict__ f0, const float* __restrict__ f1,
    const float* __restrict__ f2, const float* __restrict__ f3,
    const float* __restrict__ Wp, const float* __restrict__ bp,
    float* __restrict__ w0, float* __restrict__ w1,
    float* __restrict__ w2, float* __restrict__ w3)
{
    __shared__ short As[2 * 128 * LDT];
    __shared__ short Bs[2 * 128 * LDT];
    const int by = blockIdx.y, bx = blockIdx.x;
    if (by < 128) {
        gemm_body<float, short, false>(As, Bs, q, Wz, bz, z, 256, by * 128, bx * 128);
    } else {
        const int y = by - 128;
        const float* A; float* C; int m0;
        if      (y < 128) { A = f0; C = w0; m0 = y * 128; }
        else if (y < 160) { A = f1; C = w1; m0 = (y - 128) * 128; }
        else if (y < 168) { A = f2; C = w2; m0 = (y - 160) * 128; }
        else              { A = f3; C = w3; m0 = (y - 168) * 128; }
        gemm_body<float, float, true>(As, Bs, A, Wp, bp, C, 256, m0, bx * 128);
    }
}

// D2: zo GEMM (by<256) + za GEMM (by>=256), one dispatch
__global__ __launch_bounds__(256) void gemm_zo_za(
    const short* __restrict__ z,
    const float* __restrict__ Wo, const float* __restrict__ bo, short* __restrict__ zo,
    const float* __restrict__ Wa, const float* __restrict__ ba, short* __restrict__ za)
{
    __shared__ short As[128 * LDT];
    __shared__ short Bs[128 * LDT];
    const int by = blockIdx.y;
    if (by < 256)
        gemm_body<short, short, false>(As, Bs, z, Wo, bo, zo, 256, (by >> 1) * 128, (by & 1) * 128);
    else
        gemm_body<short, short, false>(As, Bs, z, Wa, ba, za, 128, (by - 256) * 128, 0);
}

// D3: softmax over s=16; za bf16 [b][q][128] -> attn f32 [b][p][m][16]
__global__ __launch_bounds__(256) void softmax3(const short* __restrict__ za, float* __restrict__ attn)
{
    const int tid  = blockIdx.x * 256 + threadIdx.x;  // (b*4096+qpos)*8 + m
    const int m    = tid & 7;
    const int row  = tid >> 3;  // b*4096 + qpos
    const short* zp = za + (size_t)row * 128 + m * 16;
    float v[16];
    #pragma unroll
    for (int i = 0; i < 16; ++i) v[i] = bf2f(zp[i]);
    float mx = v[0];
    #pragma unroll
    for (int i = 1; i < 16; ++i) mx = fmaxf(mx, v[i]);
    float s = 0.f;
    #pragma unroll
    for (int i = 0; i < 16; ++i) { v[i] = expf(v[i] - mx); s += v[i]; }
    const float inv = 1.f / s;
    float* op = attn + ((size_t)row * 8 + m) * 16;
    #pragma unroll
    for (int i = 0; i < 16; ++i) op[i] = v[i] * inv;
}

// D4: sample. Block per (b,qy,qx) via XCD-swizzled bid; t = l*64 + k*16 + m*2 + hi.
// Wave = one level (wp pointer in SGPR); per k-group the 16 lanes cover a
// contiguous 1KB pixel slice; 4 nearby k-points share lines through L1.
__global__ __launch_bounds__(256) void sample4(
    const short* __restrict__ zo,      // bf16 [b][qy][qx][256]
    const float* __restrict__ attn,    // f32 [b][p][m][16]
    const float* __restrict__ ref,     // f32 [BS][64][64][2]
    const float* __restrict__ wp0, const float* __restrict__ wp1,
    const float* __restrict__ wp2, const float* __restrict__ wp3,
    float* __restrict__ outp)          // f32 [b][p][256]
{
    const int bid = blockIdx.x;
    const int blk = (bid & 7) * 2048 + (bid >> 3);   // XCD-contiguous query bands
    const int qx = blk & 63;
    const int qy = (blk >> 6) & 63;
    const int b  = blk >> 12;
    const int t  = threadIdx.x;
    const int hi = t & 1;
    const int m  = (t >> 1) & 7;
    const int k  = (t >> 4) & 3;
    const int l  = t >> 6;               // wave-uniform

    const int ya = qy >> 2, yb = qy & 3;
    const int p  = (k << 10) | (qx << 4) | ya;
    const int c  = m * 32 + yb * 8 + l * 2 + hi;

    const int hw = 64 >> l;
    const float fw = (float)hw;
    const float* wp = (l == 0) ? wp0 : (l == 1) ? wp1 : (l == 2) ? wp2 : wp3;

    // learned offset (bf16 pair, 4B aligned)
    const unsigned off2 = *(const unsigned*)(zo + (size_t)blk * 256 + ((m * 4 + l) * 4 + k) * 2);
    const float offx = bf2f((short)(off2 & 0xffff));
    const float offy = bf2f((short)(off2 >> 16));

    const int rb = m & 3;
    const float2 rr = *(const float2*)(ref + ((size_t)(rb * 4096) + qy * 64 + qx) * 2);

    const float px  = rr.x * (fw - 1.f) + offx;
    const float py  = rr.y * (fw - 1.f) + offy;
    const float gx  = 2.f * px / (fw - 1.f) - 1.f;
    const float gy  = 2.f * py / (fw - 1.f) - 1.f;
    const float xim = (gx + 1.f) * (fw * 0.5f) - 0.5f;
    const float yim = (gy + 1.f) * (fw * 0.5f) - 0.5f;

    const float x0f = floorf(xim), y0f = floorf(yim);
    const float wx1 = xim - x0f, wy1 = yim - y0f;
    const float wx0 = 1.f - wx1, wy0 = 1.f - wy1;
    const int ix0 = (int)x0f, iy0 = (int)y0f;

    float w[16];
    {
        const float4* ap = (const float4*)(attn + (((size_t)b * 4096 + p) * 8 + m) * 16);
        #pragma unroll
        for (int i = 0; i < 4; ++i) {
            float4 f = ap[i];
            w[4*i] = f.x; w[4*i+1] = f.y; w[4*i+2] = f.z; w[4*i+3] = f.w;
        }
    }

    const size_t chb = (size_t)m * 32 + hi * 16;
    float r = 0.f;
    #pragma unroll
    for (int tap = 0; tap < 4; ++tap) {
        int iy = iy0 + (tap >> 1);
        int ix = ix0 + (tap & 1);
        const bool ok = (iy >= 0) & (iy < hw) & (ix >= 0) & (ix < hw);
        float wt = ((tap >> 1) ? wy1 : wy0) * ((tap & 1) ? wx1 : wx0);
        wt = ok ? wt : 0.f;
        iy = min(max(iy, 0), hw - 1);
        ix = min(max(ix, 0), hw - 1);
        const float4* tp = (const float4*)(wp + (((size_t)b * hw + iy) * hw + ix) * 256 + chb);
        const float4 t0 = tp[0], t1 = tp[1], t2 = tp[2], t3 = tp[3];
        float d = t0.x*w[0]  + t0.y*w[1]  + t0.z*w[2]  + t0.w*w[3]
                + t1.x*w[4]  + t1.y*w[5]  + t1.z*w[6]  + t1.w*w[7]
                + t2.x*w[8]  + t2.y*w[9]  + t2.z*w[10] + t2.w*w[11]
                + t3.x*w[12] + t3.y*w[13] + t3.z*w[14] + t3.w*w[15];
        r += wt * d;
    }

    outp[((size_t)b * 4096 + p) * 256 + c] = r;
}

// D5: final GEMM
__global__ __launch_bounds__(256) void gemm_final(
    const float* __restrict__ A, const float* __restrict__ B,
    const float* __restrict__ bias, float* __restrict__ C)
{
    __shared__ short As[2 * 128 * LDT];
    __shared__ short Bs[2 * 128 * LDT];
    gemm_body<float, float, true>(As, Bs, A, B, bias, C, 256, blockIdx.y * 128, blockIdx.x * 128);
}

extern "C" void kernel_launch(void* const* d_in, const int* in_sizes, int n_in,
                              void* d_out, int out_size, void* d_ws, size_t ws_size,
                              hipStream_t stream)
{
    const float* q   = (const float*)d_in[0];
    const float* ref = (const float*)d_in[1];
    const float* f0  = (const float*)d_in[2];
    const float* f1  = (const float*)d_in[3];
    const float* f2  = (const float*)d_in[4];
    const float* f3  = (const float*)d_in[5];
    const float* Wz  = (const float*)d_in[6];
    const float* bz  = (const float*)d_in[7];
    const float* Wo  = (const float*)d_in[8];
    const float* bo  = (const float*)d_in[9];
    const float* Wa  = (const float*)d_in[10];
    const float* ba  = (const float*)d_in[11];
    const float* Wp  = (const float*)d_in[12];
    const float* bp  = (const float*)d_in[13];
    const float* Wm  = (const float*)d_in[14];
    const float* bm  = (const float*)d_in[15];
    float* out = (float*)d_out;

    char* ws = (char*)d_ws;
    short* z    = (short*)(ws + ((size_t)0));         // bf16 8MB
    short* za   = (short*)(ws + ((size_t)8  << 20));  // bf16 4MB
    short* zo   = (short*)(ws + ((size_t)16 << 20));  // bf16 8MB
    float* attn = (float*)(ws + ((size_t)28 << 20));  // f32 8MB
    float* wp0  = (float*)(ws + ((size_t)36 << 20));  // f32 16MB
    float* wp1  = (float*)(ws + ((size_t)52 << 20));  // f32 4MB
    float* wp2  = (float*)(ws + ((size_t)56 << 20));  // f32 1MB
    float* wp3  = (float*)(ws + ((size_t)57 << 20));  // f32 0.25MB
    float* outp = (float*)(ws + ((size_t)0));         // f32 16MB (z/za dead)

    const dim3 blk(256);

    // D1: z = bf16(q@Wz+bz) AND wp_l = feat_l@Wp+bp (split)
    gemm_z_wp<<<dim3(2, 298), blk, 0, stream>>>(q, Wz, bz, z,
                                                f0, f1, f2, f3, Wp, bp,
                                                wp0, wp1, wp2, wp3);
    // D2: zo = bf16(z@Wo+bo) AND za = bf16(z@Wa+ba)
    gemm_zo_za<<<dim3(1, 384), blk, 0, stream>>>(z, Wo, bo, zo, Wa, ba, za);
    // D3: softmax -> attn [b][p][m][16]
    softmax3<<<dim3(512), blk, 0, stream>>>(za, attn);
    // D4: sampling -> out_pre (overwrites z/za region)
    sample4<<<dim3(16384), blk, 0, stream>>>(zo, attn, ref, wp0, wp1, wp2, wp3, outp);
    // D5: out = out_pre@Wm+bm (split)
    gemm_final<<<dim3(2, 128), blk, 0, stream>>>(outp, Wm, bm, out);
}

// Round 5
// 109.526 us; speedup vs baseline: 1.3872x; 1.3872x over previous
//
#include <hip/hip_runtime.h>
#include <hip/hip_bf16.h>

// DeformableAttention: BS=4, Hq=Wq=64, C=256, M=8, K=4, L=4, CV=32
// SCALES = 64,32,16,8
//
// Dispatches (5):
//  D1 gemm_z_wp : z = bf16(q@Wz+bz)  AND  wp_l = bf16(feat_l@Wp+bp) (split compute, bf16 store)
//  D2 gemm_zo_za: zo = bf16(z@Wo+bo) AND  za = bf16(z@Wa+ba)
//  D3 softmax   : za -> attn [b][p][m][16] f32
//  D4 sample    : wave=level, 8-lane cluster=(k,hi) per (m,l) -> out_pre f32
//  D5 gemm final: out = out_pre@Wm+bm (bf16x3 split, f32 store)
//
// ws layout (MB): z@0(8) za@8(4) zo@16(8) attn@28(8)
//   wp0@36(8) wp1@44(2) wp2@46(0.5) wp3@46.5(0.125); out_pre@0(16). Peak 46.6 MB.

typedef __attribute__((ext_vector_type(8))) short short8;
typedef __attribute__((ext_vector_type(4))) float f32x4;

constexpr int LDT = 40;  // LDS row stride (bf16 elems)

__device__ __forceinline__ short f2bf(float x) {
    unsigned u = __builtin_bit_cast(unsigned, x);
    unsigned r = (u + 0x7fffu + ((u >> 16) & 1u)) >> 16;
    return (short)r;
}
__device__ __forceinline__ float bf2f(short s) {
    unsigned u = ((unsigned)(unsigned short)s) << 16;
    return __builtin_bit_cast(float, u);
}

// ---------------------------------------------------------------------------
// GEMM body: C[tile 128x128 at (m0,n0)] = A[rows x 256] @ B[256 x N] + bias
// ---------------------------------------------------------------------------
template<typename AT, typename OT, bool SPLIT>
__device__ __forceinline__ void gemm_body(
    short* __restrict__ As, short* __restrict__ Bs,
    const AT* __restrict__ A, const float* __restrict__ B,
    const float* __restrict__ bias, OT* __restrict__ C,
    int N, int m0, int n0)
{
    short* Asl = As + 128 * LDT;
    short* Bsl = Bs + 128 * LDT;

    const int t    = threadIdx.x;
    const int lane = t & 63, wid = t >> 6;
    const int wr = wid >> 1, wc = wid & 1;
    const int lr = lane & 15, lkb = (lane >> 4) * 8;

    const int arow = t >> 1, akoff = (t & 1) * 16;
    const int bn = t & 127, bkoff = (t >> 7) * 16;

    f32x4 acc[4][4] = {};

    for (int kt = 0; kt < 256; kt += 32) {
        if constexpr (sizeof(AT) == 4) {
            const float* ap = (const float*)A + (size_t)(m0 + arow) * 256 + kt + akoff;
            float v[16];
            #pragma unroll
            for (int i = 0; i < 4; ++i) {
                float4 f = ((const float4*)ap)[i];
                v[4*i] = f.x; v[4*i+1] = f.y; v[4*i+2] = f.z; v[4*i+3] = f.w;
            }
            short8 h0, h1;
            #pragma unroll
            for (int i = 0; i < 8; ++i) { h0[i] = f2bf(v[i]); h1[i] = f2bf(v[8+i]); }
            *(short8*)&As[arow*LDT + akoff]     = h0;
            *(short8*)&As[arow*LDT + akoff + 8] = h1;
            if constexpr (SPLIT) {
                short8 l0, l1;
                #pragma unroll
                for (int i = 0; i < 8; ++i) {
                    l0[i] = f2bf(v[i]   - bf2f(h0[i]));
                    l1[i] = f2bf(v[8+i] - bf2f(h1[i]));
                }
                *(short8*)&Asl[arow*LDT + akoff]     = l0;
                *(short8*)&Asl[arow*LDT + akoff + 8] = l1;
            }
        } else {
            const short* ap = (const short*)A + (size_t)(m0 + arow) * 256 + kt + akoff;
            *(short8*)&As[arow*LDT + akoff]     = ((const short8*)ap)[0];
            *(short8*)&As[arow*LDT + akoff + 8] = ((const short8*)ap)[1];
        }
        {
            const float* bp = B + (size_t)(kt + bkoff) * N + n0 + bn;
            float v[16];
            #pragma unroll
            for (int i = 0; i < 16; ++i) v[i] = bp[(size_t)i * N];
            short8 h0, h1;
            #pragma unroll
            for (int i = 0; i < 8; ++i) { h0[i] = f2bf(v[i]); h1[i] = f2bf(v[8+i]); }
            *(short8*)&Bs[bn*LDT + bkoff]     = h0;
            *(short8*)&Bs[bn*LDT + bkoff + 8] = h1;
            if constexpr (SPLIT) {
                short8 l0, l1;
                #pragma unroll
                for (int i = 0; i < 8; ++i) {
                    l0[i] = f2bf(v[i]   - bf2f(h0[i]));
                    l1[i] = f2bf(v[8+i] - bf2f(h1[i]));
                }
                *(short8*)&Bsl[bn*LDT + bkoff]     = l0;
                *(short8*)&Bsl[bn*LDT + bkoff + 8] = l1;
            }
        }
        __syncthreads();

        short8 af[4], bfh[4];
        #pragma unroll
        for (int m = 0; m < 4; ++m)
            af[m] = *(const short8*)&As[(wr*64 + m*16 + lr)*LDT + lkb];
        #pragma unroll
        for (int n = 0; n < 4; ++n)
            bfh[n] = *(const short8*)&Bs[(wc*64 + n*16 + lr)*LDT + lkb];
        if constexpr (!SPLIT) {
            #pragma unroll
            for (int m = 0; m < 4; ++m)
                #pragma unroll
                for (int n = 0; n < 4; ++n)
                    acc[m][n] = __builtin_amdgcn_mfma_f32_16x16x32_bf16(af[m], bfh[n], acc[m][n], 0, 0, 0);
        } else {
            short8 afl[4], bfl[4];
            #pragma unroll
            for (int m = 0; m < 4; ++m)
                afl[m] = *(const short8*)&Asl[(wr*64 + m*16 + lr)*LDT + lkb];
            #pragma unroll
            for (int n = 0; n < 4; ++n)
                bfl[n] = *(const short8*)&Bsl[(wc*64 + n*16 + lr)*LDT + lkb];
            #pragma unroll
            for (int m = 0; m < 4; ++m)
                #pragma unroll
                for (int n = 0; n < 4; ++n) {
                    acc[m][n] = __builtin_amdgcn_mfma_f32_16x16x32_bf16(af[m],  bfh[n], acc[m][n], 0, 0, 0);
                    acc[m][n] = __builtin_amdgcn_mfma_f32_16x16x32_bf16(af[m],  bfl[n], acc[m][n], 0, 0, 0);
                    acc[m][n] = __builtin_amdgcn_mfma_f32_16x16x32_bf16(afl[m], bfh[n], acc[m][n], 0, 0, 0);
                }
        }
        __syncthreads();
    }

    #pragma unroll
    for (int n = 0; n < 4; ++n) {
        const int col = n0 + wc*64 + n*16 + lr;
        const float bv = bias[col];
        #pragma unroll
        for (int m = 0; m < 4; ++m) {
            #pragma unroll
            for (int r = 0; r < 4; ++r) {
                const int row = m0 + wr*64 + m*16 + (lane >> 4)*4 + r;
                const float v = acc[m][n][r] + bv;
                if constexpr (sizeof(OT) == 4)
                    ((float*)C)[(size_t)row * N + col] = v;
                else
                    ((short*)C)[(size_t)row * N + col] = f2bf(v);
            }
        }
    }
}

// D1: z GEMM (by<128) + all 4 wp GEMMs (by>=128, split compute -> bf16 store)
__global__ __launch_bounds__(256) void gemm_z_wp(
    const float* __restrict__ q, const float* __restrict__ Wz,
    const float* __restrict__ bz, short* __restrict__ z,
    const float* __restrict__ f0, const float* __restrict__ f1,
    const float* __restrict__ f2, const float* __restrict__ f3,
    const float* __restrict__ Wp, const float* __restrict__ bp,
    short* __restrict__ w0, short* __restrict__ w1,
    short* __restrict__ w2, short* __restrict__ w3)
{
    __shared__ short As[2 * 128 * LDT];
    __shared__ short Bs[2 * 128 * LDT];
    const int by = blockIdx.y, bx = blockIdx.x;
    if (by < 128) {
        gemm_body<float, short, false>(As, Bs, q, Wz, bz, z, 256, by * 128, bx * 128);
    } else {
        const int y = by - 128;
        const float* A; short* C; int m0;
        if      (y < 128) { A = f0; C = w0; m0 = y * 128; }
        else if (y < 160) { A = f1; C = w1; m0 = (y - 128) * 128; }
        else if (y < 168) { A = f2; C = w2; m0 = (y - 160) * 128; }
        else              { A = f3; C = w3; m0 = (y - 168) * 128; }
        gemm_body<float, short, true>(As, Bs, A, Wp, bp, C, 256, m0, bx * 128);
    }
}

// D2: zo GEMM (by<256) + za GEMM (by>=256), one dispatch
__global__ __launch_bounds__(256) void gemm_zo_za(
    const short* __restrict__ z,
    const float* __restrict__ Wo, const float* __restrict__ bo, short* __restrict__ zo,
    const float* __restrict__ Wa, const float* __restrict__ ba, short* __restrict__ za)
{
    __shared__ short As[128 * LDT];
    __shared__ short Bs[128 * LDT];
    const int by = blockIdx.y;
    if (by < 256)
        gemm_body<short, short, false>(As, Bs, z, Wo, bo, zo, 256, (by >> 1) * 128, (by & 1) * 128);
    else
        gemm_body<short, short, false>(As, Bs, z, Wa, ba, za, 128, (by - 256) * 128, 0);
}

// D3: softmax over s=16; za bf16 [b][q][128] -> attn f32 [b][p][m][16]
__global__ __launch_bounds__(256) void softmax3(const short* __restrict__ za, float* __restrict__ attn)
{
    const int tid  = blockIdx.x * 256 + threadIdx.x;  // (b*4096+qpos)*8 + m
    const int m    = tid & 7;
    const int row  = tid >> 3;  // b*4096 + qpos
    const short* zp = za + (size_t)row * 128 + m * 16;
    float v[16];
    #pragma unroll
    for (int i = 0; i < 16; ++i) v[i] = bf2f(zp[i]);
    float mx = v[0];
    #pragma unroll
    for (int i = 1; i < 16; ++i) mx = fmaxf(mx, v[i]);
    float s = 0.f;
    #pragma unroll
    for (int i = 0; i < 16; ++i) { v[i] = expf(v[i] - mx); s += v[i]; }
    const float inv = 1.f / s;
    float* op = attn + ((size_t)row * 8 + m) * 16;
    #pragma unroll
    for (int i = 0; i < 16; ++i) op[i] = v[i] * inv;
}

// D4: sample. Block per (b,qy,qx) via XCD-swizzled bid.
// t = l*64 + m*8 + k*2 + hi: wave = one level (wp ptr in SGPR);
// 8-lane cluster = fixed (m,l), varying (k,hi) -> the 4 k-points share one
// ref point +- small offsets, so their bilinear taps hit the same bf16
// cache lines (one pixel's 32-ch m-slice = 64B), deduped through L1.
__global__ __launch_bounds__(256) void sample5(
    const short* __restrict__ zo,      // bf16 [b][qy][qx][256]
    const float* __restrict__ attn,    // f32 [b][p][m][16]
    const float* __restrict__ ref,     // f32 [BS][64][64][2]
    const short* __restrict__ wp0, const short* __restrict__ wp1,
    const short* __restrict__ wp2, const short* __restrict__ wp3,
    float* __restrict__ outp)          // f32 [b][p][256]
{
    const int bid = blockIdx.x;
    const int blk = (bid & 7) * 2048 + (bid >> 3);   // XCD-contiguous query bands
    const int qx = blk & 63;
    const int qy = (blk >> 6) & 63;
    const int b  = blk >> 12;
    const int t  = threadIdx.x;
    const int hi = t & 1;
    const int k  = (t >> 1) & 3;
    const int m  = (t >> 3) & 7;
    const int l  = t >> 6;               // wave-uniform

    const int ya = qy >> 2, yb = qy & 3;
    const int p  = (k << 10) | (qx << 4) | ya;
    const int c  = m * 32 + yb * 8 + l * 2 + hi;

    const int hw = 64 >> l;
    const float fw = (float)hw;
    const short* wp = (l == 0) ? wp0 : (l == 1) ? wp1 : (l == 2) ? wp2 : wp3;

    // learned offset (bf16 pair, 4B aligned)
    const unsigned off2 = *(const unsigned*)(zo + (size_t)blk * 256 + ((m * 4 + l) * 4 + k) * 2);
    const float offx = bf2f((short)(off2 & 0xffff));
    const float offy = bf2f((short)(off2 >> 16));

    const int rb = m & 3;
    const float2 rr = *(const float2*)(ref + ((size_t)(rb * 4096) + qy * 64 + qx) * 2);

    const float px  = rr.x * (fw - 1.f) + offx;
    const float py  = rr.y * (fw - 1.f) + offy;
    const float gx  = 2.f * px / (fw - 1.f) - 1.f;
    const float gy  = 2.f * py / (fw - 1.f) - 1.f;
    const float xim = (gx + 1.f) * (fw * 0.5f) - 0.5f;
    const float yim = (gy + 1.f) * (fw * 0.5f) - 0.5f;

    const float x0f = floorf(xim), y0f = floorf(yim);
    const float wx1 = xim - x0f, wy1 = yim - y0f;
    const float wx0 = 1.f - wx1, wy0 = 1.f - wy1;
    const int ix0 = (int)x0f, iy0 = (int)y0f;

    float w[16];
    {
        const float4* ap = (const float4*)(attn + (((size_t)b * 4096 + p) * 8 + m) * 16);
        #pragma unroll
        for (int i = 0; i < 4; ++i) {
            float4 f = ap[i];
            w[4*i] = f.x; w[4*i+1] = f.y; w[4*i+2] = f.z; w[4*i+3] = f.w;
        }
    }

    const size_t chb = (size_t)m * 32 + hi * 16;
    float r = 0.f;
    #pragma unroll
    for (int tap = 0; tap < 4; ++tap) {
        int iy = iy0 + (tap >> 1);
        int ix = ix0 + (tap & 1);
        const bool ok = (iy >= 0) & (iy < hw) & (ix >= 0) & (ix < hw);
        float wt = ((tap >> 1) ? wy1 : wy0) * ((tap & 1) ? wx1 : wx0);
        wt = ok ? wt : 0.f;
        iy = min(max(iy, 0), hw - 1);
        ix = min(max(ix, 0), hw - 1);
        const short8* tp = (const short8*)(wp + (((size_t)b * hw + iy) * hw + ix) * 256 + chb);
        const short8 t0 = tp[0], t1 = tp[1];
        float d = 0.f;
        #pragma unroll
        for (int j = 0; j < 8; ++j) d += bf2f(t0[j]) * w[j];
        #pragma unroll
        for (int j = 0; j < 8; ++j) d += bf2f(t1[j]) * w[8 + j];
        r += wt * d;
    }

    outp[((size_t)b * 4096 + p) * 256 + c] = r;
}

// D5: final GEMM
__global__ __launch_bounds__(256) void gemm_final(
    const float* __restrict__ A, const float* __restrict__ B,
    const float* __restrict__ bias, float* __restrict__ C)
{
    __shared__ short As[2 * 128 * LDT];
    __shared__ short Bs[2 * 128 * LDT];
    gemm_body<float, float, true>(As, Bs, A, B, bias, C, 256, blockIdx.y * 128, blockIdx.x * 128);
}

extern "C" void kernel_launch(void* const* d_in, const int* in_sizes, int n_in,
                              void* d_out, int out_size, void* d_ws, size_t ws_size,
                              hipStream_t stream)
{
    const float* q   = (const float*)d_in[0];
    const float* ref = (const float*)d_in[1];
    const float* f0  = (const float*)d_in[2];
    const float* f1  = (const float*)d_in[3];
    const float* f2  = (const float*)d_in[4];
    const float* f3  = (const float*)d_in[5];
    const float* Wz  = (const float*)d_in[6];
    const float* bz  = (const float*)d_in[7];
    const float* Wo  = (const float*)d_in[8];
    const float* bo  = (const float*)d_in[9];
    const float* Wa  = (const float*)d_in[10];
    const float* ba  = (const float*)d_in[11];
    const float* Wp  = (const float*)d_in[12];
    const float* bp  = (const float*)d_in[13];
    const float* Wm  = (const float*)d_in[14];
    const float* bm  = (const float*)d_in[15];
    float* out = (float*)d_out;

    char* ws = (char*)d_ws;
    short* z    = (short*)(ws + ((size_t)0));          // bf16 8MB
    short* za   = (short*)(ws + ((size_t)8  << 20));   // bf16 4MB
    short* zo   = (short*)(ws + ((size_t)16 << 20));   // bf16 8MB
    float* attn = (float*)(ws + ((size_t)28 << 20));   // f32 8MB
    short* wp0  = (short*)(ws + ((size_t)36 << 20));   // bf16 8MB
    short* wp1  = (short*)(ws + ((size_t)44 << 20));   // bf16 2MB
    short* wp2  = (short*)(ws + ((size_t)46 << 20));   // bf16 0.5MB
    short* wp3  = (short*)(ws + ((size_t)46 << 20) + ((size_t)512 << 10)); // bf16 0.125MB
    float* outp = (float*)(ws + ((size_t)0));          // f32 16MB (z/za dead)

    const dim3 blk(256);

    // D1: z = bf16(q@Wz+bz) AND wp_l = bf16(feat_l@Wp+bp) (split compute)
    gemm_z_wp<<<dim3(2, 298), blk, 0, stream>>>(q, Wz, bz, z,
                                                f0, f1, f2, f3, Wp, bp,
                                                wp0, wp1, wp2, wp3);
    // D2: zo = bf16(z@Wo+bo) AND za = bf16(z@Wa+ba)
    gemm_zo_za<<<dim3(1, 384), blk, 0, stream>>>(z, Wo, bo, zo, Wa, ba, za);
    // D3: softmax -> attn [b][p][m][16]
    softmax3<<<dim3(512), blk, 0, stream>>>(za, attn);
    // D4: sampling -> out_pre (overwrites z/za region)
    sample5<<<dim3(16384), blk, 0, stream>>>(zo, attn, ref, wp0, wp1, wp2, wp3, outp);
    // D5: out = out_pre@Wm+bm (split)
    gemm_final<<<dim3(2, 128), blk, 0, stream>>>(outp, Wm, bm, out);
}

// Round 6
// 99.295 us; speedup vs baseline: 1.5301x; 1.1030x over previous
//
#include <hip/hip_runtime.h>
#include <hip/hip_bf16.h>

// DeformableAttention: BS=4, Hq=Wq=64, C=256, M=8, K=4, L=4, CV=32
// SCALES = 64,32,16,8
//
// All-f16 pipeline (f16 rel err 2^-11, 8x finer than bf16; all tensors
// magnitude-bounded so range is safe; single f16 MFMA ~= bf16x3 split):
//  D1 gemm_z_wp : z = f16(q@Wz+bz)  AND  wp_l = f16(feat_l@Wp+bp)
//  D2 gemm_zo_za: zo = f16(z@Wo+bo) AND  za = f16(z@Wa+ba)
//  D3 softmax   : za -> attn f16 [b][p][m][16]
//  D4 sample    : wave=level, k in low lane bits, hi-merged (32ch/lane),
//                 v_dot2_f32_f16 inner dot -> out_pre f32
//  D5 gemm final: out = out_pre@Wm+bm -> f32
//
// ws (MB): z@0(8) za@8(4) zo@16(8) attn@24(4)
//   wp0@28(8) wp1@36(2) wp2@38(.5) wp3@38.5(.125); out_pre@0(16). Peak 38.6.

typedef __attribute__((ext_vector_type(8))) _Float16 half8;
typedef __attribute__((ext_vector_type(2))) _Float16 half2t;
typedef __attribute__((ext_vector_type(4))) float f32x4;

constexpr int LDT = 40;  // LDS row stride (f16 elems) = 80B

#if __has_builtin(__builtin_amdgcn_fdot2)
__device__ __forceinline__ float fdot2f(half2t a, half2t b, float c) {
    return __builtin_amdgcn_fdot2(a, b, c, false);
}
#else
__device__ __forceinline__ float fdot2f(half2t a, half2t b, float c) {
    return c + (float)a.x * (float)b.x + (float)a.y * (float)b.y;
}
#endif

// ---------------------------------------------------------------------------
// GEMM body: C[tile 128x128 at (m0,n0)] = A[rows x 256] @ B[256 x N] + bias
// f16 MFMA 16x16x32. AT in {float, _Float16}; OT in {float, _Float16}.
// ---------------------------------------------------------------------------
template<typename AT, typename OT>
__device__ __forceinline__ void gemm_body(
    _Float16* __restrict__ As, _Float16* __restrict__ Bs,
    const AT* __restrict__ A, const float* __restrict__ B,
    const float* __restrict__ bias, OT* __restrict__ C,
    int N, int m0, int n0)
{
    const int t    = threadIdx.x;
    const int lane = t & 63, wid = t >> 6;
    const int wr = wid >> 1, wc = wid & 1;
    const int lr = lane & 15, lkb = (lane >> 4) * 8;

    const int arow = t >> 1, akoff = (t & 1) * 16;
    const int bn = t & 127, bkoff = (t >> 7) * 16;

    f32x4 acc[4][4] = {};

    for (int kt = 0; kt < 256; kt += 32) {
        // stage A tile [128 x 32]
        if constexpr (sizeof(AT) == 4) {
            const float* ap = (const float*)A + (size_t)(m0 + arow) * 256 + kt + akoff;
            float v[16];
            #pragma unroll
            for (int i = 0; i < 4; ++i) {
                float4 f = ((const float4*)ap)[i];
                v[4*i] = f.x; v[4*i+1] = f.y; v[4*i+2] = f.z; v[4*i+3] = f.w;
            }
            half8 h0, h1;
            #pragma unroll
            for (int i = 0; i < 8; ++i) { h0[i] = (_Float16)v[i]; h1[i] = (_Float16)v[8+i]; }
            *(half8*)&As[arow*LDT + akoff]     = h0;
            *(half8*)&As[arow*LDT + akoff + 8] = h1;
        } else {
            const _Float16* ap = (const _Float16*)A + (size_t)(m0 + arow) * 256 + kt + akoff;
            *(half8*)&As[arow*LDT + akoff]     = ((const half8*)ap)[0];
            *(half8*)&As[arow*LDT + akoff + 8] = ((const half8*)ap)[1];
        }
        // stage B tile [32 x 128] transposed -> Bs[n][k]
        {
            const float* bp = B + (size_t)(kt + bkoff) * N + n0 + bn;
            float v[16];
            #pragma unroll
            for (int i = 0; i < 16; ++i) v[i] = bp[(size_t)i * N];
            half8 h0, h1;
            #pragma unroll
            for (int i = 0; i < 8; ++i) { h0[i] = (_Float16)v[i]; h1[i] = (_Float16)v[8+i]; }
            *(half8*)&Bs[bn*LDT + bkoff]     = h0;
            *(half8*)&Bs[bn*LDT + bkoff + 8] = h1;
        }
        __syncthreads();

        half8 af[4], bf[4];
        #pragma unroll
        for (int m = 0; m < 4; ++m)
            af[m] = *(const half8*)&As[(wr*64 + m*16 + lr)*LDT + lkb];
        #pragma unroll
        for (int n = 0; n < 4; ++n)
            bf[n] = *(const half8*)&Bs[(wc*64 + n*16 + lr)*LDT + lkb];
        #pragma unroll
        for (int m = 0; m < 4; ++m)
            #pragma unroll
            for (int n = 0; n < 4; ++n)
                acc[m][n] = __builtin_amdgcn_mfma_f32_16x16x32_f16(af[m], bf[n], acc[m][n], 0, 0, 0);
        __syncthreads();
    }

    #pragma unroll
    for (int n = 0; n < 4; ++n) {
        const int col = n0 + wc*64 + n*16 + lr;
        const float bv = bias[col];
        #pragma unroll
        for (int m = 0; m < 4; ++m) {
            #pragma unroll
            for (int r = 0; r < 4; ++r) {
                const int row = m0 + wr*64 + m*16 + (lane >> 4)*4 + r;
                const float v = acc[m][n][r] + bv;
                if constexpr (sizeof(OT) == 4)
                    ((float*)C)[(size_t)row * N + col] = v;
                else
                    ((_Float16*)C)[(size_t)row * N + col] = (_Float16)v;
            }
        }
    }
}

// D1: z GEMM (by<128) + all 4 wp GEMMs (by>=128)
__global__ __launch_bounds__(256) void gemm_z_wp(
    const float* __restrict__ q, const float* __restrict__ Wz,
    const float* __restrict__ bz, _Float16* __restrict__ z,
    const float* __restrict__ f0, const float* __restrict__ f1,
    const float* __restrict__ f2, const float* __restrict__ f3,
    const float* __restrict__ Wp, const float* __restrict__ bp,
    _Float16* __restrict__ w0, _Float16* __restrict__ w1,
    _Float16* __restrict__ w2, _Float16* __restrict__ w3)
{
    __shared__ _Float16 As[128 * LDT];
    __shared__ _Float16 Bs[128 * LDT];
    const int by = blockIdx.y, bx = blockIdx.x;
    if (by < 128) {
        gemm_body<float, _Float16>(As, Bs, q, Wz, bz, z, 256, by * 128, bx * 128);
    } else {
        const int y = by - 128;
        const float* A; _Float16* C; int m0;
        if      (y < 128) { A = f0; C = w0; m0 = y * 128; }
        else if (y < 160) { A = f1; C = w1; m0 = (y - 128) * 128; }
        else if (y < 168) { A = f2; C = w2; m0 = (y - 160) * 128; }
        else              { A = f3; C = w3; m0 = (y - 168) * 128; }
        gemm_body<float, _Float16>(As, Bs, A, Wp, bp, C, 256, m0, bx * 128);
    }
}

// D2: zo GEMM (by<256) + za GEMM (by>=256)
__global__ __launch_bounds__(256) void gemm_zo_za(
    const _Float16* __restrict__ z,
    const float* __restrict__ Wo, const float* __restrict__ bo, _Float16* __restrict__ zo,
    const float* __restrict__ Wa, const float* __restrict__ ba, _Float16* __restrict__ za)
{
    __shared__ _Float16 As[128 * LDT];
    __shared__ _Float16 Bs[128 * LDT];
    const int by = blockIdx.y;
    if (by < 256)
        gemm_body<_Float16, _Float16>(As, Bs, z, Wo, bo, zo, 256, (by >> 1) * 128, (by & 1) * 128);
    else
        gemm_body<_Float16, _Float16>(As, Bs, z, Wa, ba, za, 128, (by - 256) * 128, 0);
}

// D3: softmax over s=16; za f16 [b][q][128] -> attn f16 [b][p][m][16]
__global__ __launch_bounds__(256) void softmax3(const _Float16* __restrict__ za, _Float16* __restrict__ attn)
{
    const int tid  = blockIdx.x * 256 + threadIdx.x;  // (b*4096+qpos)*8 + m
    const int m    = tid & 7;
    const int row  = tid >> 3;  // b*4096 + qpos
    const half8* zp = (const half8*)(za + (size_t)row * 128 + m * 16);
    const half8 a = zp[0], bvec = zp[1];
    float v[16];
    #pragma unroll
    for (int i = 0; i < 8; ++i) { v[i] = (float)a[i]; v[8+i] = (float)bvec[i]; }
    float mx = v[0];
    #pragma unroll
    for (int i = 1; i < 16; ++i) mx = fmaxf(mx, v[i]);
    float s = 0.f;
    #pragma unroll
    for (int i = 0; i < 16; ++i) { v[i] = expf(v[i] - mx); s += v[i]; }
    const float inv = 1.f / s;
    half8 o0, o1;
    #pragma unroll
    for (int i = 0; i < 8; ++i) { o0[i] = (_Float16)(v[i] * inv); o1[i] = (_Float16)(v[8+i] * inv); }
    half8* op = (half8*)(attn + ((size_t)row * 8 + m) * 16);
    op[0] = o0; op[1] = o1;
}

// D4: sample. Block = 2 queries (XCD-swizzled); t = l*64 + q'*32 + m*4 + k.
// Wave = one level (wp ptr SGPR-uniform); 4-lane cluster = (k) per (q',m):
// the 4 k-points share one ref point +- small offsets -> taps hit the same
// f16 cache lines. Each lane does both hi halves (32 ch) via v_dot2_f32_f16.
__global__ __launch_bounds__(256) void sample6(
    const _Float16* __restrict__ zo,    // f16 [b][qy][qx][256]
    const _Float16* __restrict__ attn,  // f16 [b][p][m][16]
    const float* __restrict__ ref,      // f32 [BS][64][64][2]
    const _Float16* __restrict__ wp0, const _Float16* __restrict__ wp1,
    const _Float16* __restrict__ wp2, const _Float16* __restrict__ wp3,
    float* __restrict__ outp)           // f32 [b][p][256]
{
    const int bid = blockIdx.x;
    const int bp_ = (bid & 7) * 1024 + (bid >> 3);   // XCD-contiguous bands (8192 blocks)
    const int t  = threadIdx.x;
    const int k  = t & 3;
    const int m  = (t >> 2) & 7;
    const int qp = (t >> 5) & 1;
    const int l  = t >> 6;               // wave-uniform

    const int query = bp_ * 2 + qp;      // b*4096 + qy*64 + qx
    const int qx = query & 63;
    const int qy = (query >> 6) & 63;
    const int b  = query >> 12;

    const int ya = qy >> 2, yb = qy & 3;
    const int p  = (k << 10) | (qx << 4) | ya;
    const int cb = m * 32 + yb * 8 + l * 2;

    const int hw = 64 >> l;
    const float fw = (float)hw;
    const _Float16* wp = (l == 0) ? wp0 : (l == 1) ? wp1 : (l == 2) ? wp2 : wp3;

    // learned offset (f16 pair, 4B aligned)
    const unsigned off2 = *(const unsigned*)(zo + (size_t)query * 256 + ((m * 4 + l) * 4 + k) * 2);
    const half2t offh = __builtin_bit_cast(half2t, off2);
    const float offx = (float)offh.x;
    const float offy = (float)offh.y;

    const int rb = m & 3;
    const float2 rr = *(const float2*)(ref + ((size_t)(rb * 4096) + qy * 64 + qx) * 2);

    const float px  = rr.x * (fw - 1.f) + offx;
    const float py  = rr.y * (fw - 1.f) + offy;
    const float gx  = 2.f * px / (fw - 1.f) - 1.f;
    const float gy  = 2.f * py / (fw - 1.f) - 1.f;
    const float xim = (gx + 1.f) * (fw * 0.5f) - 0.5f;
    const float yim = (gy + 1.f) * (fw * 0.5f) - 0.5f;

    const float x0f = floorf(xim), y0f = floorf(yim);
    const float wx1 = xim - x0f, wy1 = yim - y0f;
    const float wx0 = 1.f - wx1, wy0 = 1.f - wy1;
    const int ix0 = (int)x0f, iy0 = (int)y0f;

    // attn weights: 16 f16 = 8 half2
    half2t w[8];
    {
        const uint4* ap = (const uint4*)(attn + (((size_t)b * 4096 + p) * 8 + m) * 16);
        const uint4 wa = ap[0], wb = ap[1];
        w[0] = __builtin_bit_cast(half2t, wa.x); w[1] = __builtin_bit_cast(half2t, wa.y);
        w[2] = __builtin_bit_cast(half2t, wa.z); w[3] = __builtin_bit_cast(half2t, wa.w);
        w[4] = __builtin_bit_cast(half2t, wb.x); w[5] = __builtin_bit_cast(half2t, wb.y);
        w[6] = __builtin_bit_cast(half2t, wb.z); w[7] = __builtin_bit_cast(half2t, wb.w);
    }

    float r0 = 0.f, r1 = 0.f;
    #pragma unroll
    for (int tap = 0; tap < 4; ++tap) {
        int iy = iy0 + (tap >> 1);
        int ix = ix0 + (tap & 1);
        const bool ok = (iy >= 0) & (iy < hw) & (ix >= 0) & (ix < hw);
        float wt = ((tap >> 1) ? wy1 : wy0) * ((tap & 1) ? wx1 : wx0);
        wt = ok ? wt : 0.f;
        iy = min(max(iy, 0), hw - 1);
        ix = min(max(ix, 0), hw - 1);
        const uint4* tp = (const uint4*)(wp + (((size_t)b * hw + iy) * hw + ix) * 256 + m * 32);
        const uint4 u0 = tp[0], u1 = tp[1], u2 = tp[2], u3 = tp[3];
        float d0 = 0.f, d1 = 0.f;
        d0 = fdot2f(__builtin_bit_cast(half2t, u0.x), w[0], d0);
        d0 = fdot2f(__builtin_bit_cast(half2t, u0.y), w[1], d0);
        d0 = fdot2f(__builtin_bit_cast(half2t, u0.z), w[2], d0);
        d0 = fdot2f(__builtin_bit_cast(half2t, u0.w), w[3], d0);
        d0 = fdot2f(__builtin_bit_cast(half2t, u1.x), w[4], d0);
        d0 = fdot2f(__builtin_bit_cast(half2t, u1.y), w[5], d0);
        d0 = fdot2f(__builtin_bit_cast(half2t, u1.z), w[6], d0);
        d0 = fdot2f(__builtin_bit_cast(half2t, u1.w), w[7], d0);
        d1 = fdot2f(__builtin_bit_cast(half2t, u2.x), w[0], d1);
        d1 = fdot2f(__builtin_bit_cast(half2t, u2.y), w[1], d1);
        d1 = fdot2f(__builtin_bit_cast(half2t, u2.z), w[2], d1);
        d1 = fdot2f(__builtin_bit_cast(half2t, u2.w), w[3], d1);
        d1 = fdot2f(__builtin_bit_cast(half2t, u3.x), w[4], d1);
        d1 = fdot2f(__builtin_bit_cast(half2t, u3.y), w[5], d1);
        d1 = fdot2f(__builtin_bit_cast(half2t, u3.z), w[6], d1);
        d1 = fdot2f(__builtin_bit_cast(half2t, u3.w), w[7], d1);
        r0 += wt * d0;
        r1 += wt * d1;
    }

    *(float2*)(outp + ((size_t)b * 4096 + p) * 256 + cb) = make_float2(r0, r1);
}

// D5: final GEMM (f32 out)
__global__ __launch_bounds__(256) void gemm_final(
    const float* __restrict__ A, const float* __restrict__ B,
    const float* __restrict__ bias, float* __restrict__ C)
{
    __shared__ _Float16 As[128 * LDT];
    __shared__ _Float16 Bs[128 * LDT];
    gemm_body<float, float>(As, Bs, A, B, bias, C, 256, blockIdx.y * 128, blockIdx.x * 128);
}

extern "C" void kernel_launch(void* const* d_in, const int* in_sizes, int n_in,
                              void* d_out, int out_size, void* d_ws, size_t ws_size,
                              hipStream_t stream)
{
    const float* q   = (const float*)d_in[0];
    const float* ref = (const float*)d_in[1];
    const float* f0  = (const float*)d_in[2];
    const float* f1  = (const float*)d_in[3];
    const float* f2  = (const float*)d_in[4];
    const float* f3  = (const float*)d_in[5];
    const float* Wz  = (const float*)d_in[6];
    const float* bz  = (const float*)d_in[7];
    const float* Wo  = (const float*)d_in[8];
    const float* bo  = (const float*)d_in[9];
    const float* Wa  = (const float*)d_in[10];
    const float* ba  = (const float*)d_in[11];
    const float* Wp  = (const float*)d_in[12];
    const float* bp  = (const float*)d_in[13];
    const float* Wm  = (const float*)d_in[14];
    const float* bm  = (const float*)d_in[15];
    float* out = (float*)d_out;

    char* ws = (char*)d_ws;
    _Float16* z    = (_Float16*)(ws + ((size_t)0));          // f16 8MB
    _Float16* za   = (_Float16*)(ws + ((size_t)8  << 20));   // f16 4MB
    _Float16* zo   = (_Float16*)(ws + ((size_t)16 << 20));   // f16 8MB
    _Float16* attn = (_Float16*)(ws + ((size_t)24 << 20));   // f16 4MB
    _Float16* wp0  = (_Float16*)(ws + ((size_t)28 << 20));   // f16 8MB
    _Float16* wp1  = (_Float16*)(ws + ((size_t)36 << 20));   // f16 2MB
    _Float16* wp2  = (_Float16*)(ws + ((size_t)38 << 20));   // f16 0.5MB
    _Float16* wp3  = (_Float16*)(ws + ((size_t)38 << 20) + ((size_t)512 << 10)); // 0.125MB
    float*    outp = (float*)(ws + ((size_t)0));             // f32 16MB (z/za dead)

    const dim3 blk(256);

    // D1: z = f16(q@Wz+bz) AND wp_l = f16(feat_l@Wp+bp)
    gemm_z_wp<<<dim3(2, 298), blk, 0, stream>>>(q, Wz, bz, z,
                                                f0, f1, f2, f3, Wp, bp,
                                                wp0, wp1, wp2, wp3);
    // D2: zo = f16(z@Wo+bo) AND za = f16(z@Wa+ba)
    gemm_zo_za<<<dim3(1, 384), blk, 0, stream>>>(z, Wo, bo, zo, Wa, ba, za);
    // D3: softmax -> attn f16 [b][p][m][16]
    softmax3<<<dim3(512), blk, 0, stream>>>(za, attn);
    // D4: sampling -> out_pre (overwrites z/za region)
    sample6<<<dim3(8192), blk, 0, stream>>>(zo, attn, ref, wp0, wp1, wp2, wp3, outp);
    // D5: out = out_pre@Wm+bm
    gemm_final<<<dim3(2, 128), blk, 0, stream>>>(outp, Wm, bm, out);
}